// Round 3
// baseline (543.880 us; speedup 1.0000x reference)
//
#include <hip/hip_runtime.h>
#include <stdint.h>

#define MROWS 8192   // B*S
#define DM    1024
#define NH    16
#define HD    64
#define SEQ   2048

typedef __bf16 bf16x8 __attribute__((ext_vector_type(8)));
typedef __bf16 bf16x4 __attribute__((ext_vector_type(4)));
typedef float  floatx4 __attribute__((ext_vector_type(4)));

// 0.125 (1/sqrt(64)) * log2(e): folded into Q so flash scores are already base-2
#define QSCALE 0.18033688011112042f

__device__ __forceinline__ void async16(const void* g, void* l) {
  __builtin_amdgcn_global_load_lds(
      (__attribute__((address_space(1))) void*)g,
      (__attribute__((address_space(3))) void*)l,
      16, 0, 0);
}

__device__ __forceinline__ floatx4 mfma16(bf16x8 a, bf16x8 b, floatx4 c) {
  return __builtin_amdgcn_mfma_f32_16x16x32_bf16(a, b, c, 0, 0, 0);
}

// DPP lane permutes within 16-lane rows (pure VALU, no LDS)
template <int CTRL>
__device__ __forceinline__ float dpp_mov(float x) {
  return __builtin_bit_cast(float,
      __builtin_amdgcn_update_dpp(0, __builtin_bit_cast(int, x), CTRL, 0xF, 0xF, true));
}
__device__ __forceinline__ float red16_max(float x) {
  x = fmaxf(x, dpp_mov<0xB1>(x));
  x = fmaxf(x, dpp_mov<0x4E>(x));
  x = fmaxf(x, dpp_mov<0x124>(x));
  x = fmaxf(x, dpp_mov<0x128>(x));
  return x;
}
__device__ __forceinline__ float red16_sum(float x) {
  x += dpp_mov<0xB1>(x);
  x += dpp_mov<0x4E>(x);
  x += dpp_mov<0x124>(x);
  x += dpp_mov<0x128>(x);
  return x;
}

// ---------------- conversion kernels ----------------

__global__ void __launch_bounds__(256) split_x_kernel(const float* __restrict__ x,
                                                      __bf16* __restrict__ xh,
                                                      __bf16* __restrict__ xl) {
  const int i = blockIdx.x * 256 + threadIdx.x;
  const float4 v = reinterpret_cast<const float4*>(x)[i];
  const float vv[4] = {v.x, v.y, v.z, v.w};
  bf16x4 H, L;
#pragma unroll
  for (int j = 0; j < 4; ++j) {
    const __bf16 h = (__bf16)vv[j];
    H[j] = h;
    L[j] = (__bf16)(vv[j] - (float)h);
  }
  reinterpret_cast<bf16x4*>(xh)[i] = H;
  reinterpret_cast<bf16x4*>(xl)[i] = L;
}

// W [K=1024][N=1024] fp32 -> W^T [N][K] bf16 hi (+ optional lo)
__global__ void __launch_bounds__(256) wtrans_kernel(const float* __restrict__ W,
                                                     __bf16* __restrict__ Th,
                                                     __bf16* __restrict__ Tl) {
  __shared__ float t[32][33];
  const int tx = threadIdx.x & 31, ty = threadIdx.x >> 5;
  const int bx = blockIdx.x & 31, by = blockIdx.x >> 5;
#pragma unroll
  for (int j = 0; j < 4; ++j) {
    const int k = by * 32 + ty + j * 8;
    t[ty + j * 8][tx] = W[(size_t)k * DM + bx * 32 + tx];
  }
  __syncthreads();
#pragma unroll
  for (int j = 0; j < 4; ++j) {
    const int n = bx * 32 + ty + j * 8;
    const int k = by * 32 + tx;
    const float v = t[tx][ty + j * 8];
    const __bf16 h = (__bf16)v;
    Th[(size_t)n * DM + k] = h;
    if (Tl) Tl[(size_t)n * DM + k] = (__bf16)(v - (float)h);
  }
}

// ---------------- NT GEMM: C[M,N] = A[M,K] * B^T  (B given as [N,K]) ----------------
// TERMS==3: 3-term hi/lo split product (drops lo*lo).
// OUTMODE: 0 = bf16, 1 = fp32, 2 = bf16 hi/lo split (scaled by oscale before split),
//          3 = bf16 transposed per-head: Vt[b,h,d,s]
template <int TERMS, int OUTMODE>
__global__ void __launch_bounds__(256) gemm_nt(const __bf16* __restrict__ Ah,
                                               const __bf16* __restrict__ Al,
                                               const __bf16* __restrict__ Bh,
                                               const __bf16* __restrict__ Bl,
                                               void* __restrict__ C0,
                                               void* __restrict__ C1,
                                               float oscale) {
  __shared__ __align__(16) __bf16 sAh[128 * 32];
  __shared__ __align__(16) __bf16 sBh[128 * 32];
  __shared__ __align__(16) __bf16 sAl[(TERMS == 3) ? 128 * 32 : 8];
  __shared__ __align__(16) __bf16 sBl[(TERMS == 3) ? 128 * 32 : 8];

  const int tid = threadIdx.x;
  const int bm = blockIdx.x >> 3;
  const int bn = blockIdx.x & 7;
  const int m0 = bm << 7, n0 = bn << 7;
  const int w = tid >> 6;
  const int lane = tid & 63;
  const int wm = (w >> 1) << 6;
  const int wn = (w & 1) << 6;
  const int lm = lane & 15;
  const int q4 = lane >> 4;

  floatx4 acc[4][4];
  const floatx4 fz = {0.f, 0.f, 0.f, 0.f};
#pragma unroll
  for (int i = 0; i < 4; ++i)
#pragma unroll
    for (int j = 0; j < 4; ++j) acc[i][j] = fz;

  const int c0 = tid, c1 = tid + 256;
  const int row0 = c0 >> 2, cc0 = (c0 & 3) ^ ((row0 >> 1) & 3);
  const int row1 = c1 >> 2, cc1 = (c1 & 3) ^ ((row1 >> 1) & 3);

  int offA[4], offB[4];
#pragma unroll
  for (int i = 0; i < 4; ++i) {
    const int ra = wm + i * 16 + lm;
    offA[i] = ra * 32 + ((q4 ^ ((ra >> 1) & 3)) << 3);
    const int rb = wn + i * 16 + lm;
    offB[i] = rb * 32 + ((q4 ^ ((rb >> 1) & 3)) << 3);
  }

  // rolling global offsets (advance by 32 elems per K-iter)
  size_t ga0 = (size_t)(m0 + row0) * DM + cc0 * 8;
  size_t gb0 = (size_t)(n0 + row0) * DM + cc0 * 8;
  size_t ga1 = (size_t)(m0 + row1) * DM + cc1 * 8;
  size_t gb1 = (size_t)(n0 + row1) * DM + cc1 * 8;

  for (int it = 0; it < 32; ++it) {
    async16(Ah + ga0, &sAh[c0 * 8]);
    async16(Bh + gb0, &sBh[c0 * 8]);
    async16(Ah + ga1, &sAh[c1 * 8]);
    async16(Bh + gb1, &sBh[c1 * 8]);
    if constexpr (TERMS == 3) {
      async16(Al + ga0, &sAl[c0 * 8]);
      async16(Bl + gb0, &sBl[c0 * 8]);
      async16(Al + ga1, &sAl[c1 * 8]);
      async16(Bl + gb1, &sBl[c1 * 8]);
    }
    ga0 += 32; gb0 += 32; ga1 += 32; gb1 += 32;
    __syncthreads();

    bf16x8 ah[4], bh[4], al[4], bl[4];
#pragma unroll
    for (int i = 0; i < 4; ++i) {
      ah[i] = *(const bf16x8*)&sAh[offA[i]];
      bh[i] = *(const bf16x8*)&sBh[offB[i]];
      if constexpr (TERMS == 3) {
        al[i] = *(const bf16x8*)&sAl[offA[i]];
        bl[i] = *(const bf16x8*)&sBl[offB[i]];
      }
    }
#pragma unroll
    for (int i = 0; i < 4; ++i)
#pragma unroll
      for (int j = 0; j < 4; ++j) {
        acc[i][j] = mfma16(ah[i], bh[j], acc[i][j]);
        if constexpr (TERMS == 3) {
          acc[i][j] = mfma16(ah[i], bl[j], acc[i][j]);
          acc[i][j] = mfma16(al[i], bh[j], acc[i][j]);
        }
      }
    __syncthreads();
  }

  // epilogue; C/D layout: col = lane&15, row = (lane>>4)*4 + reg
#pragma unroll
  for (int i = 0; i < 4; ++i) {
#pragma unroll
    for (int j = 0; j < 4; ++j) {
#pragma unroll
      for (int r = 0; r < 4; ++r) {
        const int gr = m0 + wm + i * 16 + q4 * 4 + r;
        const int gc = n0 + wn + j * 16 + lm;
        const float v = acc[i][j][r];
        if constexpr (OUTMODE == 0) {
          ((__bf16*)C0)[(size_t)gr * DM + gc] = (__bf16)v;
        } else if constexpr (OUTMODE == 1) {
          ((float*)C0)[(size_t)gr * DM + gc] = v;
        } else if constexpr (OUTMODE == 2) {
          const float vs = v * oscale;
          const __bf16 hv = (__bf16)vs;
          ((__bf16*)C0)[(size_t)gr * DM + gc] = hv;
          ((__bf16*)C1)[(size_t)gr * DM + gc] = (__bf16)(vs - (float)hv);
        } else {
          const int bb = gr >> 11, ss = gr & 2047;
          const int hh = gc >> 6, dd = gc & 63;
          ((__bf16*)C0)[(((size_t)(bb * NH + hh) << 6) + dd) * SEQ + ss] = (__bf16)v;
        }
      }
    }
  }
}

// ---------------- flash attention ----------------
// grid: blockIdx.x = bh*32 + qtile ; block = 256 (4 waves, each wave owns 16 q rows)
// Q pre-scaled by 0.125*log2(e): scores are base-2 exponents directly.
// Ping-pong K/V staging: 1 barrier/iter; DMA for tile i+1 issued before compute of
// tile i covers its latency. Q's LDS (buf 1) is reclaimed as the second K buffer
// after Q moves to registers. sP is half-width (32 keys): PV runs in two halves
// with an in-wave LDS overwrite between them (per-wave-private, in-order DS pipe).
__global__ void __launch_bounds__(256) flash_kernel(const __bf16* __restrict__ Qh,
                                                    const __bf16* __restrict__ Ql,
                                                    const __bf16* __restrict__ Kh,
                                                    const __bf16* __restrict__ Kl,
                                                    const __bf16* __restrict__ Vt,
                                                    __bf16* __restrict__ Mg) {
  __shared__ __align__(16) __bf16 sKh[2][64 * 64];
  __shared__ __align__(16) __bf16 sKl[2][64 * 64];
  __shared__ __align__(16) __bf16 sV[2][64 * 64];
  __shared__ __align__(16) __bf16 sP[4][16 * 40];  // 54272 B total -> 3 blocks/CU

  const int tid = threadIdx.x;
  const int qt = blockIdx.x & 31;
  const int bh = blockIdx.x >> 5;
  const int b = bh >> 4;
  const int h = bh & 15;
  const int mq0 = b * SEQ + qt * 64;
  const int ch = h * 64;
  const int w = tid >> 6;
  const int lane = tid & 63;
  const int lm = lane & 15;
  const int q4 = lane >> 4;

  // staging geometry: two 16B chunks per thread, swizzle chunk ^ (row&7)
  const int c0 = tid, c1 = tid + 256;
  const int r0 = c0 >> 3, e0 = ((c0 & 7) ^ (r0 & 7)) << 3;
  const int r1 = c1 >> 3, e1 = ((c1 & 7) ^ (r1 & 7)) << 3;

  // prologue: Q -> buf1, K/V tile 0 -> buf0
  {
    const size_t gq0 = (size_t)(mq0 + r0) * DM + ch + e0;
    const size_t gq1 = (size_t)(mq0 + r1) * DM + ch + e1;
    async16(Qh + gq0, &sKh[1][c0 * 8]);
    async16(Ql + gq0, &sKl[1][c0 * 8]);
    async16(Qh + gq1, &sKh[1][c1 * 8]);
    async16(Ql + gq1, &sKl[1][c1 * 8]);
    const size_t k0a = (size_t)(b * SEQ + r0) * DM + ch + e0;
    const size_t k0b = (size_t)(b * SEQ + r1) * DM + ch + e1;
    async16(Kh + k0a, &sKh[0][c0 * 8]);
    async16(Kl + k0a, &sKl[0][c0 * 8]);
    async16(Kh + k0b, &sKh[0][c1 * 8]);
    async16(Kl + k0b, &sKl[0][c1 * 8]);
    const size_t v0a = (size_t)(bh * 64 + r0) * SEQ + e0;
    const size_t v0b = (size_t)(bh * 64 + r1) * SEQ + e1;
    async16(Vt + v0a, &sV[0][c0 * 8]);
    async16(Vt + v0b, &sV[0][c1 * 8]);
  }

  // rolling offsets for prefetch of tile it+1
  size_t gk0 = (size_t)(b * SEQ + 64 + r0) * DM + ch + e0;
  size_t gk1 = (size_t)(b * SEQ + 64 + r1) * DM + ch + e1;
  size_t gv0 = (size_t)(bh * 64 + r0) * SEQ + 64 + e0;
  size_t gv1 = (size_t)(bh * 64 + r1) * SEQ + 64 + e1;

  // hoisted fragment LDS offsets (identical formula for K and V tiles)
  int ofr[2][4];
#pragma unroll
  for (int ks = 0; ks < 2; ++ks)
#pragma unroll
    for (int t = 0; t < 4; ++t) {
      const int rk = t * 16 + lm;
      ofr[ks][t] = rk * 64 + (((ks * 4 + q4) ^ (rk & 7)) << 3);
    }

  floatx4 o[4];
  const floatx4 fz = {0.f, 0.f, 0.f, 0.f};
#pragma unroll
  for (int dt = 0; dt < 4; ++dt) o[dt] = fz;
  float mrow[4], lrow[4];
#pragma unroll
  for (int r = 0; r < 4; ++r) { mrow[r] = -1e30f; lrow[r] = 0.f; }

  __syncthreads();  // Q (buf1) + tile0 (buf0) resident

  bf16x8 qh[2], ql[2];
  {
    const int rq = w * 16 + lm;
#pragma unroll
    for (int ks = 0; ks < 2; ++ks) {
      const int oq = rq * 64 + (((ks * 4 + q4) ^ (rq & 7)) << 3);
      qh[ks] = *(const bf16x8*)&sKh[1][oq];
      ql[ks] = *(const bf16x8*)&sKl[1][oq];
    }
  }
  __syncthreads();  // all waves hold Q in regs; buf1 reusable as K ping-pong

  const __bf16* sPr = &sP[w][lm * 40];
  __bf16* sPw = &sP[w][(q4 * 4) * 40 + lm];

  for (int it = 0; it < 32; ++it) {
    const int cur = it & 1;
    if (it < 31) {
      const int nxt = cur ^ 1;
      async16(Kh + gk0, &sKh[nxt][c0 * 8]);
      async16(Kl + gk0, &sKl[nxt][c0 * 8]);
      async16(Kh + gk1, &sKh[nxt][c1 * 8]);
      async16(Kl + gk1, &sKl[nxt][c1 * 8]);
      async16(Vt + gv0, &sV[nxt][c0 * 8]);
      async16(Vt + gv1, &sV[nxt][c1 * 8]);
      gk0 += (size_t)64 * DM;
      gk1 += (size_t)64 * DM;
      gv0 += 64;
      gv1 += 64;
    }

    const __bf16* bKh = sKh[cur];
    const __bf16* bKl = sKl[cur];
    const __bf16* bV = sV[cur];

    // scores: S[16 q x 64 key] per wave, 3-term, log2 domain
    floatx4 s[4];
#pragma unroll
    for (int nt = 0; nt < 4; ++nt) s[nt] = fz;
#pragma unroll
    for (int ks = 0; ks < 2; ++ks) {
#pragma unroll
      for (int nt = 0; nt < 4; ++nt) {
        const bf16x8 kh = *(const bf16x8*)&bKh[ofr[ks][nt]];
        const bf16x8 kl = *(const bf16x8*)&bKl[ofr[ks][nt]];
        s[nt] = mfma16(qh[ks], kh, s[nt]);
        s[nt] = mfma16(qh[ks], kl, s[nt]);
        s[nt] = mfma16(ql[ks], kh, s[nt]);
      }
    }

    // online softmax (base-2); rows q = q4*4 + r, DPP reduce over 16 lanes
    float mnew[4];
    bool upd = false;
#pragma unroll
    for (int r = 0; r < 4; ++r) {
      float mx = fmaxf(fmaxf(s[0][r], s[1][r]), fmaxf(s[2][r], s[3][r]));
      mx = red16_max(mx);
      mnew[r] = fmaxf(mrow[r], mx);
      upd = upd || (mnew[r] > mrow[r]);
    }
    if (__ballot(upd)) {
#pragma unroll
      for (int r = 0; r < 4; ++r) {
        const float a = __builtin_amdgcn_exp2f(mrow[r] - mnew[r]);
        lrow[r] *= a;
        mrow[r] = mnew[r];
#pragma unroll
        for (int dt = 0; dt < 4; ++dt) o[dt][r] *= a;
      }
    }
    float p2[4], p3[4];
#pragma unroll
    for (int r = 0; r < 4; ++r) {
      const float p0 = __builtin_amdgcn_exp2f(s[0][r] - mrow[r]);
      const float p1 = __builtin_amdgcn_exp2f(s[1][r] - mrow[r]);
      p2[r] = __builtin_amdgcn_exp2f(s[2][r] - mrow[r]);
      p3[r] = __builtin_amdgcn_exp2f(s[3][r] - mrow[r]);
      float sum = (p0 + p1) + (p2[r] + p3[r]);
      sum = red16_sum(sum);
      lrow[r] += sum;
      sPw[r * 40] = (__bf16)p0;
      sPw[r * 40 + 16] = (__bf16)p1;
    }

    // PV half 1: keys 0..31
    {
      const bf16x8 a = *(const bf16x8*)&sPr[q4 * 8];
#pragma unroll
      for (int dt = 0; dt < 4; ++dt) {
        const bf16x8 bv = *(const bf16x8*)&bV[ofr[0][dt]];
        o[dt] = mfma16(a, bv, o[dt]);
      }
    }
    // overwrite sP with keys 32..63 (per-wave private; DS pipe is in-order)
#pragma unroll
    for (int r = 0; r < 4; ++r) {
      sPw[r * 40] = (__bf16)p2[r];
      sPw[r * 40 + 16] = (__bf16)p3[r];
    }
    // PV half 2: keys 32..63
    {
      const bf16x8 a = *(const bf16x8*)&sPr[q4 * 8];
#pragma unroll
      for (int dt = 0; dt < 4; ++dt) {
        const bf16x8 bv = *(const bf16x8*)&bV[ofr[1][dt]];
        o[dt] = mfma16(a, bv, o[dt]);
      }
    }
    __syncthreads();  // publishes tile it+1 (DMA drained) + protects buffers
  }

  // epilogue: normalize and store merged [B*S, D] bf16
#pragma unroll
  for (int r = 0; r < 4; ++r) {
    const float inv = __builtin_amdgcn_rcpf(lrow[r]);
    const int gr = mq0 + w * 16 + q4 * 4 + r;
#pragma unroll
    for (int dt = 0; dt < 4; ++dt)
      Mg[(size_t)gr * DM + ch + dt * 16 + lm] = (__bf16)(o[dt][r] * inv);
  }
}

// ---------------- launch ----------------

extern "C" void kernel_launch(void* const* d_in, const int* in_sizes, int n_in,
                              void* d_out, int out_size, void* d_ws, size_t ws_size,
                              hipStream_t stream) {
  (void)in_sizes; (void)n_in; (void)out_size; (void)ws_size;
  const float* x  = (const float*)d_in[0];
  const float* Wq = (const float*)d_in[1];
  const float* Wk = (const float*)d_in[2];
  const float* Wv = (const float*)d_in[3];
  const float* fc = (const float*)d_in[4];
  float* out = (float*)d_out;

  char* base = (char*)d_ws;
  const size_t XB = (size_t)MROWS * DM * 2;  // 16 MiB
  const size_t WB = (size_t)DM * DM * 2;     // 2 MiB
  __bf16* xh  = (__bf16*)(base);
  __bf16* xl  = (__bf16*)(base + XB);
  __bf16* wqh = (__bf16*)(base + 2 * XB);
  __bf16* wql = (__bf16*)(base + 2 * XB + WB);
  __bf16* wkh = (__bf16*)(base + 2 * XB + 2 * WB);
  __bf16* wkl = (__bf16*)(base + 2 * XB + 3 * WB);
  __bf16* wvh = (__bf16*)(base + 2 * XB + 4 * WB);
  __bf16* fch = (__bf16*)(base + 2 * XB + 5 * WB);
  __bf16* Qh  = (__bf16*)(base + 2 * XB + 6 * WB);
  __bf16* Ql  = (__bf16*)(base + 3 * XB + 6 * WB);
  __bf16* Kh  = (__bf16*)(base + 4 * XB + 6 * WB);
  __bf16* Kl  = (__bf16*)(base + 5 * XB + 6 * WB);
  __bf16* Vt  = xl;  // xl dead after K projection
  __bf16* Mg  = xh;  // xh dead after V projection

  split_x_kernel<<<dim3(8192), dim3(256), 0, stream>>>(x, xh, xl);
  wtrans_kernel<<<dim3(1024), dim3(256), 0, stream>>>(Wq, wqh, wql);
  wtrans_kernel<<<dim3(1024), dim3(256), 0, stream>>>(Wk, wkh, wkl);
  wtrans_kernel<<<dim3(1024), dim3(256), 0, stream>>>(Wv, wvh, (__bf16*)nullptr);
  wtrans_kernel<<<dim3(1024), dim3(256), 0, stream>>>(fc, fch, (__bf16*)nullptr);

  // Q pre-scaled by 0.125*log2(e) so flash softmax runs in base-2 with no per-score mul
  gemm_nt<3, 2><<<dim3(512), dim3(256), 0, stream>>>(xh, xl, wqh, wql, (void*)Qh, (void*)Ql, QSCALE);
  gemm_nt<3, 2><<<dim3(512), dim3(256), 0, stream>>>(xh, xl, wkh, wkl, (void*)Kh, (void*)Kl, 1.0f);
  gemm_nt<1, 3><<<dim3(512), dim3(256), 0, stream>>>(xh, (const __bf16*)nullptr, wvh,
                                                     (const __bf16*)nullptr, (void*)Vt, (void*)nullptr, 1.0f);

  flash_kernel<<<dim3(2048), dim3(256), 0, stream>>>(Qh, Ql, Kh, Kl, Vt, Mg);

  gemm_nt<1, 1><<<dim3(512), dim3(256), 0, stream>>>(Mg, (const __bf16*)nullptr, fch,
                                                     (const __bf16*)nullptr, (void*)out, (void*)nullptr, 1.0f);
}

// Round 4
// 438.267 us; speedup vs baseline: 1.2410x; 1.2410x over previous
//
#include <hip/hip_runtime.h>
#include <stdint.h>

#define MROWS 8192   // B*S
#define DM    1024
#define NH    16
#define HD    64
#define SEQ   2048

typedef __bf16 bf16x8 __attribute__((ext_vector_type(8)));
typedef __bf16 bf16x4 __attribute__((ext_vector_type(4)));
typedef float  floatx4 __attribute__((ext_vector_type(4)));

// 0.125 (1/sqrt(64)) * log2(e): folded into Q so flash scores are already base-2
#define QSCALE 0.18033688011112042f

__device__ __forceinline__ void async16(const void* g, void* l) {
  __builtin_amdgcn_global_load_lds(
      (__attribute__((address_space(1))) void*)g,
      (__attribute__((address_space(3))) void*)l,
      16, 0, 0);
}

__device__ __forceinline__ floatx4 mfma16(bf16x8 a, bf16x8 b, floatx4 c) {
  return __builtin_amdgcn_mfma_f32_16x16x32_bf16(a, b, c, 0, 0, 0);
}

// DPP lane permutes within 16-lane rows (pure VALU, no LDS)
template <int CTRL>
__device__ __forceinline__ float dpp_mov(float x) {
  return __builtin_bit_cast(float,
      __builtin_amdgcn_update_dpp(0, __builtin_bit_cast(int, x), CTRL, 0xF, 0xF, true));
}
__device__ __forceinline__ float red16_max(float x) {
  x = fmaxf(x, dpp_mov<0xB1>(x));
  x = fmaxf(x, dpp_mov<0x4E>(x));
  x = fmaxf(x, dpp_mov<0x124>(x));
  x = fmaxf(x, dpp_mov<0x128>(x));
  return x;
}
__device__ __forceinline__ float red16_sum(float x) {
  x += dpp_mov<0xB1>(x);
  x += dpp_mov<0x4E>(x);
  x += dpp_mov<0x124>(x);
  x += dpp_mov<0x128>(x);
  return x;
}

// ---------------- conversion kernels ----------------

__global__ void __launch_bounds__(256) split_x_kernel(const float* __restrict__ x,
                                                      __bf16* __restrict__ xh,
                                                      __bf16* __restrict__ xl) {
  const int i = blockIdx.x * 256 + threadIdx.x;
  const float4 v = reinterpret_cast<const float4*>(x)[i];
  const float vv[4] = {v.x, v.y, v.z, v.w};
  bf16x4 H, L;
#pragma unroll
  for (int j = 0; j < 4; ++j) {
    const __bf16 h = (__bf16)vv[j];
    H[j] = h;
    L[j] = (__bf16)(vv[j] - (float)h);
  }
  reinterpret_cast<bf16x4*>(xh)[i] = H;
  reinterpret_cast<bf16x4*>(xl)[i] = L;
}

// W [K=1024][N=1024] fp32 -> W^T [N][K] bf16 hi (+ optional lo)
__global__ void __launch_bounds__(256) wtrans_kernel(const float* __restrict__ W,
                                                     __bf16* __restrict__ Th,
                                                     __bf16* __restrict__ Tl) {
  __shared__ float t[32][33];
  const int tx = threadIdx.x & 31, ty = threadIdx.x >> 5;
  const int bx = blockIdx.x & 31, by = blockIdx.x >> 5;
#pragma unroll
  for (int j = 0; j < 4; ++j) {
    const int k = by * 32 + ty + j * 8;
    t[ty + j * 8][tx] = W[(size_t)k * DM + bx * 32 + tx];
  }
  __syncthreads();
#pragma unroll
  for (int j = 0; j < 4; ++j) {
    const int n = bx * 32 + ty + j * 8;
    const int k = by * 32 + tx;
    const float v = t[tx][ty + j * 8];
    const __bf16 h = (__bf16)v;
    Th[(size_t)n * DM + k] = h;
    if (Tl) Tl[(size_t)n * DM + k] = (__bf16)(v - (float)h);
  }
}

// ---------------- NT GEMM (1-term): C[M,N] = A[M,K] * B^T ----------------
// OUTMODE: 1 = fp32, 3 = bf16 transposed per-head: Vt[b,h,d,s]
template <int OUTMODE>
__global__ void __launch_bounds__(256) gemm_nt(const __bf16* __restrict__ Ah,
                                               const __bf16* __restrict__ Bh,
                                               void* __restrict__ C0) {
  __shared__ __align__(16) __bf16 sAh[128 * 32];
  __shared__ __align__(16) __bf16 sBh[128 * 32];

  const int tid = threadIdx.x;
  const int bm = blockIdx.x >> 3;
  const int bn = blockIdx.x & 7;
  const int m0 = bm << 7, n0 = bn << 7;
  const int w = tid >> 6;
  const int lane = tid & 63;
  const int wm = (w >> 1) << 6;
  const int wn = (w & 1) << 6;
  const int lm = lane & 15;
  const int q4 = lane >> 4;

  floatx4 acc[4][4];
  const floatx4 fz = {0.f, 0.f, 0.f, 0.f};
#pragma unroll
  for (int i = 0; i < 4; ++i)
#pragma unroll
    for (int j = 0; j < 4; ++j) acc[i][j] = fz;

  const int c0 = tid, c1 = tid + 256;
  const int row0 = c0 >> 2, cc0 = (c0 & 3) ^ ((row0 >> 1) & 3);
  const int row1 = c1 >> 2, cc1 = (c1 & 3) ^ ((row1 >> 1) & 3);

  int offA[4], offB[4];
#pragma unroll
  for (int i = 0; i < 4; ++i) {
    const int ra = wm + i * 16 + lm;
    offA[i] = ra * 32 + ((q4 ^ ((ra >> 1) & 3)) << 3);
    const int rb = wn + i * 16 + lm;
    offB[i] = rb * 32 + ((q4 ^ ((rb >> 1) & 3)) << 3);
  }

  size_t ga0 = (size_t)(m0 + row0) * DM + cc0 * 8;
  size_t gb0 = (size_t)(n0 + row0) * DM + cc0 * 8;
  size_t ga1 = (size_t)(m0 + row1) * DM + cc1 * 8;
  size_t gb1 = (size_t)(n0 + row1) * DM + cc1 * 8;

  for (int it = 0; it < 32; ++it) {
    async16(Ah + ga0, &sAh[c0 * 8]);
    async16(Bh + gb0, &sBh[c0 * 8]);
    async16(Ah + ga1, &sAh[c1 * 8]);
    async16(Bh + gb1, &sBh[c1 * 8]);
    ga0 += 32; gb0 += 32; ga1 += 32; gb1 += 32;
    __syncthreads();

    bf16x8 ah[4], bh[4];
#pragma unroll
    for (int i = 0; i < 4; ++i) {
      ah[i] = *(const bf16x8*)&sAh[offA[i]];
      bh[i] = *(const bf16x8*)&sBh[offB[i]];
    }
#pragma unroll
    for (int i = 0; i < 4; ++i)
#pragma unroll
      for (int j = 0; j < 4; ++j)
        acc[i][j] = mfma16(ah[i], bh[j], acc[i][j]);
    __syncthreads();
  }

#pragma unroll
  for (int i = 0; i < 4; ++i) {
#pragma unroll
    for (int j = 0; j < 4; ++j) {
#pragma unroll
      for (int r = 0; r < 4; ++r) {
        const int gr = m0 + wm + i * 16 + q4 * 4 + r;
        const int gc = n0 + wn + j * 16 + lm;
        const float v = acc[i][j][r];
        if constexpr (OUTMODE == 1) {
          ((float*)C0)[(size_t)gr * DM + gc] = v;
        } else {
          const int bb = gr >> 11, ss = gr & 2047;
          const int hh = gc >> 6, dd = gc & 63;
          ((__bf16*)C0)[(((size_t)(bb * NH + hh) << 6) + dd) * SEQ + ss] = (__bf16)v;
        }
      }
    }
  }
}

// ---------------- fused Q+K projection GEMM ----------------
// C_q = A*Bq^T (scaled by QSCALE, hi/lo split), C_k = A*Bk^T (hi/lo split).
// Shares A staging and A fragments across both outputs. 3-term hi/lo product.
__global__ void __launch_bounds__(256, 2) gemm_qk(const __bf16* __restrict__ Ah,
                                                  const __bf16* __restrict__ Al,
                                                  const __bf16* __restrict__ Bqh,
                                                  const __bf16* __restrict__ Bql,
                                                  const __bf16* __restrict__ Bkh,
                                                  const __bf16* __restrict__ Bkl,
                                                  __bf16* __restrict__ Qh,
                                                  __bf16* __restrict__ Ql,
                                                  __bf16* __restrict__ Kh,
                                                  __bf16* __restrict__ Kl) {
  __shared__ __align__(16) __bf16 sAh[128 * 32];
  __shared__ __align__(16) __bf16 sAl[128 * 32];
  __shared__ __align__(16) __bf16 sQh_[128 * 32];
  __shared__ __align__(16) __bf16 sQl_[128 * 32];
  __shared__ __align__(16) __bf16 sKh_[128 * 32];
  __shared__ __align__(16) __bf16 sKl_[128 * 32];

  const int tid = threadIdx.x;
  const int bm = blockIdx.x >> 3;
  const int bn = blockIdx.x & 7;
  const int m0 = bm << 7, n0 = bn << 7;
  const int w = tid >> 6;
  const int lane = tid & 63;
  const int wm = (w >> 1) << 6;
  const int wn = (w & 1) << 6;
  const int lm = lane & 15;
  const int q4 = lane >> 4;

  floatx4 accq[4][4], acck[4][4];
  const floatx4 fz = {0.f, 0.f, 0.f, 0.f};
#pragma unroll
  for (int i = 0; i < 4; ++i)
#pragma unroll
    for (int j = 0; j < 4; ++j) { accq[i][j] = fz; acck[i][j] = fz; }

  const int c0 = tid, c1 = tid + 256;
  const int row0 = c0 >> 2, cc0 = (c0 & 3) ^ ((row0 >> 1) & 3);
  const int row1 = c1 >> 2, cc1 = (c1 & 3) ^ ((row1 >> 1) & 3);

  int offA[4], offB[4];
#pragma unroll
  for (int i = 0; i < 4; ++i) {
    const int ra = wm + i * 16 + lm;
    offA[i] = ra * 32 + ((q4 ^ ((ra >> 1) & 3)) << 3);
    const int rb = wn + i * 16 + lm;
    offB[i] = rb * 32 + ((q4 ^ ((rb >> 1) & 3)) << 3);
  }

  size_t ga0 = (size_t)(m0 + row0) * DM + cc0 * 8;
  size_t gb0 = (size_t)(n0 + row0) * DM + cc0 * 8;
  size_t ga1 = (size_t)(m0 + row1) * DM + cc1 * 8;
  size_t gb1 = (size_t)(n0 + row1) * DM + cc1 * 8;

  for (int it = 0; it < 32; ++it) {
    async16(Ah + ga0, &sAh[c0 * 8]);
    async16(Al + ga0, &sAl[c0 * 8]);
    async16(Ah + ga1, &sAh[c1 * 8]);
    async16(Al + ga1, &sAl[c1 * 8]);
    async16(Bqh + gb0, &sQh_[c0 * 8]);
    async16(Bql + gb0, &sQl_[c0 * 8]);
    async16(Bqh + gb1, &sQh_[c1 * 8]);
    async16(Bql + gb1, &sQl_[c1 * 8]);
    async16(Bkh + gb0, &sKh_[c0 * 8]);
    async16(Bkl + gb0, &sKl_[c0 * 8]);
    async16(Bkh + gb1, &sKh_[c1 * 8]);
    async16(Bkl + gb1, &sKl_[c1 * 8]);
    ga0 += 32; gb0 += 32; ga1 += 32; gb1 += 32;
    __syncthreads();

    bf16x8 ah[4], al[4];
#pragma unroll
    for (int i = 0; i < 4; ++i) {
      ah[i] = *(const bf16x8*)&sAh[offA[i]];
      al[i] = *(const bf16x8*)&sAl[offA[i]];
    }
    // Q phase
    {
      bf16x8 bh[4], bl[4];
#pragma unroll
      for (int j = 0; j < 4; ++j) {
        bh[j] = *(const bf16x8*)&sQh_[offB[j]];
        bl[j] = *(const bf16x8*)&sQl_[offB[j]];
      }
#pragma unroll
      for (int i = 0; i < 4; ++i)
#pragma unroll
        for (int j = 0; j < 4; ++j) {
          accq[i][j] = mfma16(ah[i], bh[j], accq[i][j]);
          accq[i][j] = mfma16(ah[i], bl[j], accq[i][j]);
          accq[i][j] = mfma16(al[i], bh[j], accq[i][j]);
        }
    }
    // K phase
    {
      bf16x8 bh[4], bl[4];
#pragma unroll
      for (int j = 0; j < 4; ++j) {
        bh[j] = *(const bf16x8*)&sKh_[offB[j]];
        bl[j] = *(const bf16x8*)&sKl_[offB[j]];
      }
#pragma unroll
      for (int i = 0; i < 4; ++i)
#pragma unroll
        for (int j = 0; j < 4; ++j) {
          acck[i][j] = mfma16(ah[i], bh[j], acck[i][j]);
          acck[i][j] = mfma16(ah[i], bl[j], acck[i][j]);
          acck[i][j] = mfma16(al[i], bh[j], acck[i][j]);
        }
    }
    __syncthreads();
  }

#pragma unroll
  for (int i = 0; i < 4; ++i) {
#pragma unroll
    for (int j = 0; j < 4; ++j) {
#pragma unroll
      for (int r = 0; r < 4; ++r) {
        const int gr = m0 + wm + i * 16 + q4 * 4 + r;
        const int gc = n0 + wn + j * 16 + lm;
        const size_t idx = (size_t)gr * DM + gc;
        const float vq = accq[i][j][r] * QSCALE;
        const __bf16 qhv = (__bf16)vq;
        Qh[idx] = qhv;
        Ql[idx] = (__bf16)(vq - (float)qhv);
        const float vk = acck[i][j][r];
        const __bf16 khv = (__bf16)vk;
        Kh[idx] = khv;
        Kl[idx] = (__bf16)(vk - (float)khv);
      }
    }
  }
}

// ---------------- flash attention ----------------
// grid: blockIdx.x = bh*16 + qtile ; block = 256 (4 waves, each wave owns 32 q rows)
// Q-tile = 128 rows: halves K/V LDS-read redundancy and K/V refetch vs 64-row tiles.
// Q staged through the K buffers (2-pass prologue) then lives in registers.
// LDS = K hi/lo + V (24 KB) + sP (18 KB) = 43008 B -> 3 blocks/CU.
__global__ void __launch_bounds__(256, 3) flash_kernel(const __bf16* __restrict__ Qh,
                                                       const __bf16* __restrict__ Ql,
                                                       const __bf16* __restrict__ Kh,
                                                       const __bf16* __restrict__ Kl,
                                                       const __bf16* __restrict__ Vt,
                                                       __bf16* __restrict__ Mg) {
  __shared__ __align__(16) __bf16 sKh[64 * 64];
  __shared__ __align__(16) __bf16 sKl[64 * 64];
  __shared__ __align__(16) __bf16 sV[64 * 64];
  __shared__ __align__(16) __bf16 sP[4][32 * 72];

  const int tid = threadIdx.x;
  const int qt = blockIdx.x & 15;      // 16 q-tiles of 128
  const int bh = blockIdx.x >> 4;      // 64 (b,h) pairs
  const int b = bh >> 4;
  const int h = bh & 15;
  const int mq0 = b * SEQ + qt * 128;
  const int ch = h * 64;
  const int w = tid >> 6;
  const int lane = tid & 63;
  const int lm = lane & 15;
  const int q4 = lane >> 4;

  // staging geometry: two 16B chunks per thread, swizzle chunk ^ (row&7)
  const int c0 = tid, c1 = tid + 256;
  const int r0 = c0 >> 3, e0 = ((c0 & 7) ^ (r0 & 7)) << 3;
  const int r1 = c1 >> 3, e1 = ((c1 & 7) ^ (r1 & 7)) << 3;

  // prologue: stage Q (128 rows) in 2 passes of 64 through the K buffers -> regs
  bf16x8 qh[2][2], ql[2][2];  // [mi][ks]
#pragma unroll
  for (int p = 0; p < 2; ++p) {
    const size_t gq0 = (size_t)(mq0 + p * 64 + r0) * DM + ch + e0;
    const size_t gq1 = (size_t)(mq0 + p * 64 + r1) * DM + ch + e1;
    async16(Qh + gq0, &sKh[c0 * 8]);
    async16(Ql + gq0, &sKl[c0 * 8]);
    async16(Qh + gq1, &sKh[c1 * 8]);
    async16(Ql + gq1, &sKl[c1 * 8]);
    __syncthreads();
    if ((w >> 1) == p) {
#pragma unroll
      for (int mi = 0; mi < 2; ++mi) {
        const int rq = (w & 1) * 32 + mi * 16 + lm;  // row within this 64-row pass
#pragma unroll
        for (int ks = 0; ks < 2; ++ks) {
          const int oq = rq * 64 + (((ks * 4 + q4) ^ (rq & 7)) << 3);
          qh[mi][ks] = *(const bf16x8*)&sKh[oq];
          ql[mi][ks] = *(const bf16x8*)&sKl[oq];
        }
      }
    }
    __syncthreads();
  }

  // hoisted K/V fragment LDS offsets (same formula both)
  int ofr[2][4];
#pragma unroll
  for (int ks = 0; ks < 2; ++ks)
#pragma unroll
    for (int t = 0; t < 4; ++t) {
      const int rk = t * 16 + lm;
      ofr[ks][t] = rk * 64 + (((ks * 4 + q4) ^ (rk & 7)) << 3);
    }

  floatx4 o[2][4];
  const floatx4 fz = {0.f, 0.f, 0.f, 0.f};
#pragma unroll
  for (int mi = 0; mi < 2; ++mi)
#pragma unroll
    for (int dt = 0; dt < 4; ++dt) o[mi][dt] = fz;
  float mrow[2][4], lrow[2][4];
#pragma unroll
  for (int mi = 0; mi < 2; ++mi)
#pragma unroll
    for (int r = 0; r < 4; ++r) { mrow[mi][r] = -1e30f; lrow[mi][r] = 0.f; }

  // rolling staging offsets
  size_t gk0 = (size_t)(b * SEQ + r0) * DM + ch + e0;
  size_t gk1 = (size_t)(b * SEQ + r1) * DM + ch + e1;
  size_t gv0 = (size_t)(bh * 64 + r0) * SEQ + e0;
  size_t gv1 = (size_t)(bh * 64 + r1) * SEQ + e1;

  for (int it = 0; it < 32; ++it) {
    async16(Kh + gk0, &sKh[c0 * 8]);
    async16(Kl + gk0, &sKl[c0 * 8]);
    async16(Kh + gk1, &sKh[c1 * 8]);
    async16(Kl + gk1, &sKl[c1 * 8]);
    async16(Vt + gv0, &sV[c0 * 8]);
    async16(Vt + gv1, &sV[c1 * 8]);
    gk0 += (size_t)64 * DM;
    gk1 += (size_t)64 * DM;
    gv0 += 64;
    gv1 += 64;
    __syncthreads();

    // scores: S[32 q x 64 key] per wave, 3-term, log2 domain
    floatx4 s[2][4];
#pragma unroll
    for (int mi = 0; mi < 2; ++mi)
#pragma unroll
      for (int nt = 0; nt < 4; ++nt) s[mi][nt] = fz;
#pragma unroll
    for (int ks = 0; ks < 2; ++ks) {
#pragma unroll
      for (int nt = 0; nt < 4; ++nt) {
        const bf16x8 kh = *(const bf16x8*)&sKh[ofr[ks][nt]];
        const bf16x8 kl = *(const bf16x8*)&sKl[ofr[ks][nt]];
#pragma unroll
        for (int mi = 0; mi < 2; ++mi) {
          s[mi][nt] = mfma16(qh[mi][ks], kh, s[mi][nt]);
          s[mi][nt] = mfma16(qh[mi][ks], kl, s[mi][nt]);
          s[mi][nt] = mfma16(ql[mi][ks], kh, s[mi][nt]);
        }
      }
    }

    // online softmax (base-2); rows q = mi*16 + q4*4 + r, DPP reduce over 16 lanes
    float mnew[2][4];
    bool upd = false;
#pragma unroll
    for (int mi = 0; mi < 2; ++mi)
#pragma unroll
      for (int r = 0; r < 4; ++r) {
        float mx = fmaxf(fmaxf(s[mi][0][r], s[mi][1][r]), fmaxf(s[mi][2][r], s[mi][3][r]));
        mx = red16_max(mx);
        mnew[mi][r] = fmaxf(mrow[mi][r], mx);
        upd = upd || (mnew[mi][r] > mrow[mi][r]);
      }
    if (__ballot(upd)) {
#pragma unroll
      for (int mi = 0; mi < 2; ++mi)
#pragma unroll
        for (int r = 0; r < 4; ++r) {
          const float a = __builtin_amdgcn_exp2f(mrow[mi][r] - mnew[mi][r]);
          lrow[mi][r] *= a;
          mrow[mi][r] = mnew[mi][r];
#pragma unroll
          for (int dt = 0; dt < 4; ++dt) o[mi][dt][r] *= a;
        }
    }
#pragma unroll
    for (int mi = 0; mi < 2; ++mi)
#pragma unroll
      for (int r = 0; r < 4; ++r) {
        float p[4];
#pragma unroll
        for (int nt = 0; nt < 4; ++nt) p[nt] = __builtin_amdgcn_exp2f(s[mi][nt][r] - mrow[mi][r]);
        float sum = (p[0] + p[1]) + (p[2] + p[3]);
        sum = red16_sum(sum);
        lrow[mi][r] += sum;
        const int prow = mi * 16 + q4 * 4 + r;
#pragma unroll
        for (int nt = 0; nt < 4; ++nt)
          sP[w][prow * 72 + nt * 16 + lm] = (__bf16)p[nt];
      }

    // PV: A = P (own wave's LDS), B = V^T tile; bv shared across mi
#pragma unroll
    for (int ks = 0; ks < 2; ++ks) {
      bf16x8 a[2];
#pragma unroll
      for (int mi = 0; mi < 2; ++mi)
        a[mi] = *(const bf16x8*)&sP[w][(mi * 16 + lm) * 72 + ks * 32 + q4 * 8];
#pragma unroll
      for (int dt = 0; dt < 4; ++dt) {
        const bf16x8 bv = *(const bf16x8*)&sV[ofr[ks][dt]];
#pragma unroll
        for (int mi = 0; mi < 2; ++mi)
          o[mi][dt] = mfma16(a[mi], bv, o[mi][dt]);
      }
    }
    __syncthreads();
  }

  // epilogue: normalize and store merged [B*S, D] bf16
#pragma unroll
  for (int mi = 0; mi < 2; ++mi)
#pragma unroll
    for (int r = 0; r < 4; ++r) {
      const float inv = __builtin_amdgcn_rcpf(lrow[mi][r]);
      const int gr = mq0 + w * 32 + mi * 16 + q4 * 4 + r;
#pragma unroll
      for (int dt = 0; dt < 4; ++dt)
        Mg[(size_t)gr * DM + ch + dt * 16 + lm] = (__bf16)(o[mi][dt][r] * inv);
    }
}

// ---------------- launch ----------------

extern "C" void kernel_launch(void* const* d_in, const int* in_sizes, int n_in,
                              void* d_out, int out_size, void* d_ws, size_t ws_size,
                              hipStream_t stream) {
  (void)in_sizes; (void)n_in; (void)out_size; (void)ws_size;
  const float* x  = (const float*)d_in[0];
  const float* Wq = (const float*)d_in[1];
  const float* Wk = (const float*)d_in[2];
  const float* Wv = (const float*)d_in[3];
  const float* fc = (const float*)d_in[4];
  float* out = (float*)d_out;

  char* base = (char*)d_ws;
  const size_t XB = (size_t)MROWS * DM * 2;  // 16 MiB
  const size_t WB = (size_t)DM * DM * 2;     // 2 MiB
  __bf16* xh  = (__bf16*)(base);
  __bf16* xl  = (__bf16*)(base + XB);
  __bf16* wqh = (__bf16*)(base + 2 * XB);
  __bf16* wql = (__bf16*)(base + 2 * XB + WB);
  __bf16* wkh = (__bf16*)(base + 2 * XB + 2 * WB);
  __bf16* wkl = (__bf16*)(base + 2 * XB + 3 * WB);
  __bf16* wvh = (__bf16*)(base + 2 * XB + 4 * WB);
  __bf16* fch = (__bf16*)(base + 2 * XB + 5 * WB);
  __bf16* Qh  = (__bf16*)(base + 2 * XB + 6 * WB);
  __bf16* Ql  = (__bf16*)(base + 3 * XB + 6 * WB);
  __bf16* Kh  = (__bf16*)(base + 4 * XB + 6 * WB);
  __bf16* Kl  = (__bf16*)(base + 5 * XB + 6 * WB);
  __bf16* Vt  = xl;  // xl dead after QK projection
  __bf16* Mg  = xh;  // xh dead after V projection

  split_x_kernel<<<dim3(8192), dim3(256), 0, stream>>>(x, xh, xl);
  wtrans_kernel<<<dim3(1024), dim3(256), 0, stream>>>(Wq, wqh, wql);
  wtrans_kernel<<<dim3(1024), dim3(256), 0, stream>>>(Wk, wkh, wkl);
  wtrans_kernel<<<dim3(1024), dim3(256), 0, stream>>>(Wv, wvh, (__bf16*)nullptr);
  wtrans_kernel<<<dim3(1024), dim3(256), 0, stream>>>(fc, fch, (__bf16*)nullptr);

  // fused Q+K projection (Q pre-scaled by 0.125*log2(e) for base-2 flash softmax)
  gemm_qk<<<dim3(512), dim3(256), 0, stream>>>(xh, xl, wqh, wql, wkh, wkl, Qh, Ql, Kh, Kl);
  gemm_nt<3><<<dim3(512), dim3(256), 0, stream>>>(xh, wvh, (void*)Vt);

  flash_kernel<<<dim3(1024), dim3(256), 0, stream>>>(Qh, Ql, Kh, Kl, Vt, Mg);

  gemm_nt<1><<<dim3(512), dim3(256), 0, stream>>>(Mg, fch, (void*)out);
}

// Round 5
// 428.374 us; speedup vs baseline: 1.2696x; 1.0231x over previous
//
#include <hip/hip_runtime.h>
#include <stdint.h>

#define MROWS 8192   // B*S
#define DM    1024
#define NH    16
#define HD    64
#define SEQ   2048

typedef __bf16 bf16x8 __attribute__((ext_vector_type(8)));
typedef __bf16 bf16x4 __attribute__((ext_vector_type(4)));
typedef float  floatx4 __attribute__((ext_vector_type(4)));

// 0.125 (1/sqrt(64)) * log2(e): folded into Q so flash scores are already base-2
#define QSCALE 0.18033688011112042f

__device__ __forceinline__ void async16(const void* g, void* l) {
  __builtin_amdgcn_global_load_lds(
      (__attribute__((address_space(1))) void*)g,
      (__attribute__((address_space(3))) void*)l,
      16, 0, 0);
}

__device__ __forceinline__ floatx4 mfma16(bf16x8 a, bf16x8 b, floatx4 c) {
  return __builtin_amdgcn_mfma_f32_16x16x32_bf16(a, b, c, 0, 0, 0);
}

// DPP lane permutes within 16-lane rows (pure VALU, no LDS)
template <int CTRL>
__device__ __forceinline__ float dpp_mov(float x) {
  return __builtin_bit_cast(float,
      __builtin_amdgcn_update_dpp(0, __builtin_bit_cast(int, x), CTRL, 0xF, 0xF, true));
}
__device__ __forceinline__ float red16_max(float x) {
  x = fmaxf(x, dpp_mov<0xB1>(x));
  x = fmaxf(x, dpp_mov<0x4E>(x));
  x = fmaxf(x, dpp_mov<0x124>(x));
  x = fmaxf(x, dpp_mov<0x128>(x));
  return x;
}

// ---------------- conversion kernels ----------------

__global__ void __launch_bounds__(256) split_x_kernel(const float* __restrict__ x,
                                                      __bf16* __restrict__ xh,
                                                      __bf16* __restrict__ xl) {
  const int i = blockIdx.x * 256 + threadIdx.x;
  const float4 v = reinterpret_cast<const float4*>(x)[i];
  const float vv[4] = {v.x, v.y, v.z, v.w};
  bf16x4 H, L;
#pragma unroll
  for (int j = 0; j < 4; ++j) {
    const __bf16 h = (__bf16)vv[j];
    H[j] = h;
    L[j] = (__bf16)(vv[j] - (float)h);
  }
  reinterpret_cast<bf16x4*>(xh)[i] = H;
  reinterpret_cast<bf16x4*>(xl)[i] = L;
}

// W [K=1024][N=1024] fp32 -> W^T [N][K] bf16 hi (+ optional lo)
__global__ void __launch_bounds__(256) wtrans_kernel(const float* __restrict__ W,
                                                     __bf16* __restrict__ Th,
                                                     __bf16* __restrict__ Tl) {
  __shared__ float t[32][33];
  const int tx = threadIdx.x & 31, ty = threadIdx.x >> 5;
  const int bx = blockIdx.x & 31, by = blockIdx.x >> 5;
#pragma unroll
  for (int j = 0; j < 4; ++j) {
    const int k = by * 32 + ty + j * 8;
    t[ty + j * 8][tx] = W[(size_t)k * DM + bx * 32 + tx];
  }
  __syncthreads();
#pragma unroll
  for (int j = 0; j < 4; ++j) {
    const int n = bx * 32 + ty + j * 8;
    const int k = by * 32 + tx;
    const float v = t[tx][ty + j * 8];
    const __bf16 h = (__bf16)v;
    Th[(size_t)n * DM + k] = h;
    if (Tl) Tl[(size_t)n * DM + k] = (__bf16)(v - (float)h);
  }
}

// ---------------- NT GEMM (1-term): C[M,N] = A[M,K] * B^T ----------------
// OUTMODE: 1 = fp32, 3 = bf16 transposed per-head: Vt[b,h,d,s]
template <int OUTMODE>
__global__ void __launch_bounds__(256) gemm_nt(const __bf16* __restrict__ Ah,
                                               const __bf16* __restrict__ Bh,
                                               void* __restrict__ C0) {
  __shared__ __align__(16) __bf16 sAh[128 * 32];
  __shared__ __align__(16) __bf16 sBh[128 * 32];

  const int tid = threadIdx.x;
  const int bm = blockIdx.x >> 3;
  const int bn = blockIdx.x & 7;
  const int m0 = bm << 7, n0 = bn << 7;
  const int w = tid >> 6;
  const int lane = tid & 63;
  const int wm = (w >> 1) << 6;
  const int wn = (w & 1) << 6;
  const int lm = lane & 15;
  const int q4 = lane >> 4;

  floatx4 acc[4][4];
  const floatx4 fz = {0.f, 0.f, 0.f, 0.f};
#pragma unroll
  for (int i = 0; i < 4; ++i)
#pragma unroll
    for (int j = 0; j < 4; ++j) acc[i][j] = fz;

  const int c0 = tid, c1 = tid + 256;
  const int row0 = c0 >> 2, cc0 = (c0 & 3) ^ ((row0 >> 1) & 3);
  const int row1 = c1 >> 2, cc1 = (c1 & 3) ^ ((row1 >> 1) & 3);

  int offA[4], offB[4];
#pragma unroll
  for (int i = 0; i < 4; ++i) {
    const int ra = wm + i * 16 + lm;
    offA[i] = ra * 32 + ((q4 ^ ((ra >> 1) & 3)) << 3);
    const int rb = wn + i * 16 + lm;
    offB[i] = rb * 32 + ((q4 ^ ((rb >> 1) & 3)) << 3);
  }

  size_t ga0 = (size_t)(m0 + row0) * DM + cc0 * 8;
  size_t gb0 = (size_t)(n0 + row0) * DM + cc0 * 8;
  size_t ga1 = (size_t)(m0 + row1) * DM + cc1 * 8;
  size_t gb1 = (size_t)(n0 + row1) * DM + cc1 * 8;

  for (int it = 0; it < 32; ++it) {
    async16(Ah + ga0, &sAh[c0 * 8]);
    async16(Bh + gb0, &sBh[c0 * 8]);
    async16(Ah + ga1, &sAh[c1 * 8]);
    async16(Bh + gb1, &sBh[c1 * 8]);
    ga0 += 32; gb0 += 32; ga1 += 32; gb1 += 32;
    __syncthreads();

    bf16x8 ah[4], bh[4];
#pragma unroll
    for (int i = 0; i < 4; ++i) {
      ah[i] = *(const bf16x8*)&sAh[offA[i]];
      bh[i] = *(const bf16x8*)&sBh[offB[i]];
    }
#pragma unroll
    for (int i = 0; i < 4; ++i)
#pragma unroll
      for (int j = 0; j < 4; ++j)
        acc[i][j] = mfma16(ah[i], bh[j], acc[i][j]);
    __syncthreads();
  }

#pragma unroll
  for (int i = 0; i < 4; ++i) {
#pragma unroll
    for (int j = 0; j < 4; ++j) {
#pragma unroll
      for (int r = 0; r < 4; ++r) {
        const int gr = m0 + wm + i * 16 + q4 * 4 + r;
        const int gc = n0 + wn + j * 16 + lm;
        const float v = acc[i][j][r];
        if constexpr (OUTMODE == 1) {
          ((float*)C0)[(size_t)gr * DM + gc] = v;
        } else {
          const int bb = gr >> 11, ss = gr & 2047;
          const int hh = gc >> 6, dd = gc & 63;
          ((__bf16*)C0)[(((size_t)(bb * NH + hh) << 6) + dd) * SEQ + ss] = (__bf16)v;
        }
      }
    }
  }
}

// ---------------- fused Q+K projection GEMM ----------------
// C_q = A*Bq^T (scaled by QSCALE, hi/lo split), C_k = A*Bk^T (hi/lo split).
// Shares A staging and A fragments across both outputs. 3-term hi/lo product.
__global__ void __launch_bounds__(256, 2) gemm_qk(const __bf16* __restrict__ Ah,
                                                  const __bf16* __restrict__ Al,
                                                  const __bf16* __restrict__ Bqh,
                                                  const __bf16* __restrict__ Bql,
                                                  const __bf16* __restrict__ Bkh,
                                                  const __bf16* __restrict__ Bkl,
                                                  __bf16* __restrict__ Qh,
                                                  __bf16* __restrict__ Ql,
                                                  __bf16* __restrict__ Kh,
                                                  __bf16* __restrict__ Kl) {
  __shared__ __align__(16) __bf16 sAh[128 * 32];
  __shared__ __align__(16) __bf16 sAl[128 * 32];
  __shared__ __align__(16) __bf16 sQh_[128 * 32];
  __shared__ __align__(16) __bf16 sQl_[128 * 32];
  __shared__ __align__(16) __bf16 sKh_[128 * 32];
  __shared__ __align__(16) __bf16 sKl_[128 * 32];

  const int tid = threadIdx.x;
  const int bm = blockIdx.x >> 3;
  const int bn = blockIdx.x & 7;
  const int m0 = bm << 7, n0 = bn << 7;
  const int w = tid >> 6;
  const int lane = tid & 63;
  const int wm = (w >> 1) << 6;
  const int wn = (w & 1) << 6;
  const int lm = lane & 15;
  const int q4 = lane >> 4;

  floatx4 accq[4][4], acck[4][4];
  const floatx4 fz = {0.f, 0.f, 0.f, 0.f};
#pragma unroll
  for (int i = 0; i < 4; ++i)
#pragma unroll
    for (int j = 0; j < 4; ++j) { accq[i][j] = fz; acck[i][j] = fz; }

  const int c0 = tid, c1 = tid + 256;
  const int row0 = c0 >> 2, cc0 = (c0 & 3) ^ ((row0 >> 1) & 3);
  const int row1 = c1 >> 2, cc1 = (c1 & 3) ^ ((row1 >> 1) & 3);

  int offA[4], offB[4];
#pragma unroll
  for (int i = 0; i < 4; ++i) {
    const int ra = wm + i * 16 + lm;
    offA[i] = ra * 32 + ((q4 ^ ((ra >> 1) & 3)) << 3);
    const int rb = wn + i * 16 + lm;
    offB[i] = rb * 32 + ((q4 ^ ((rb >> 1) & 3)) << 3);
  }

  size_t ga0 = (size_t)(m0 + row0) * DM + cc0 * 8;
  size_t gb0 = (size_t)(n0 + row0) * DM + cc0 * 8;
  size_t ga1 = (size_t)(m0 + row1) * DM + cc1 * 8;
  size_t gb1 = (size_t)(n0 + row1) * DM + cc1 * 8;

  for (int it = 0; it < 32; ++it) {
    async16(Ah + ga0, &sAh[c0 * 8]);
    async16(Al + ga0, &sAl[c0 * 8]);
    async16(Ah + ga1, &sAh[c1 * 8]);
    async16(Al + ga1, &sAl[c1 * 8]);
    async16(Bqh + gb0, &sQh_[c0 * 8]);
    async16(Bql + gb0, &sQl_[c0 * 8]);
    async16(Bqh + gb1, &sQh_[c1 * 8]);
    async16(Bql + gb1, &sQl_[c1 * 8]);
    async16(Bkh + gb0, &sKh_[c0 * 8]);
    async16(Bkl + gb0, &sKl_[c0 * 8]);
    async16(Bkh + gb1, &sKh_[c1 * 8]);
    async16(Bkl + gb1, &sKl_[c1 * 8]);
    ga0 += 32; gb0 += 32; ga1 += 32; gb1 += 32;
    __syncthreads();

    bf16x8 ah[4], al[4];
#pragma unroll
    for (int i = 0; i < 4; ++i) {
      ah[i] = *(const bf16x8*)&sAh[offA[i]];
      al[i] = *(const bf16x8*)&sAl[offA[i]];
    }
    // Q phase
    {
      bf16x8 bh[4], bl[4];
#pragma unroll
      for (int j = 0; j < 4; ++j) {
        bh[j] = *(const bf16x8*)&sQh_[offB[j]];
        bl[j] = *(const bf16x8*)&sQl_[offB[j]];
      }
#pragma unroll
      for (int i = 0; i < 4; ++i)
#pragma unroll
        for (int j = 0; j < 4; ++j) {
          accq[i][j] = mfma16(ah[i], bh[j], accq[i][j]);
          accq[i][j] = mfma16(ah[i], bl[j], accq[i][j]);
          accq[i][j] = mfma16(al[i], bh[j], accq[i][j]);
        }
    }
    // K phase
    {
      bf16x8 bh[4], bl[4];
#pragma unroll
      for (int j = 0; j < 4; ++j) {
        bh[j] = *(const bf16x8*)&sKh_[offB[j]];
        bl[j] = *(const bf16x8*)&sKl_[offB[j]];
      }
#pragma unroll
      for (int i = 0; i < 4; ++i)
#pragma unroll
        for (int j = 0; j < 4; ++j) {
          acck[i][j] = mfma16(ah[i], bh[j], acck[i][j]);
          acck[i][j] = mfma16(ah[i], bl[j], acck[i][j]);
          acck[i][j] = mfma16(al[i], bh[j], acck[i][j]);
        }
    }
    __syncthreads();
  }

#pragma unroll
  for (int i = 0; i < 4; ++i) {
#pragma unroll
    for (int j = 0; j < 4; ++j) {
#pragma unroll
      for (int r = 0; r < 4; ++r) {
        const int gr = m0 + wm + i * 16 + q4 * 4 + r;
        const int gc = n0 + wn + j * 16 + lm;
        const size_t idx = (size_t)gr * DM + gc;
        const float vq = accq[i][j][r] * QSCALE;
        const __bf16 qhv = (__bf16)vq;
        Qh[idx] = qhv;
        Ql[idx] = (__bf16)(vq - (float)qhv);
        const float vk = acck[i][j][r];
        const __bf16 khv = (__bf16)vk;
        Kh[idx] = khv;
        Kl[idx] = (__bf16)(vk - (float)khv);
      }
    }
  }
}

// ---------------- flash attention ----------------
// grid: blockIdx.x = bh*16 + qtile ; block = 256 (4 waves, each wave owns 32 q rows)
// Q-tile = 128 rows. Q staged through the K buffers (2-pass prologue) then registers.
// Row-sum of P computed by MFMA against a ones B-fragment (reuses the PV A-fragment),
// removing the DPP sum reduction from the VALU path. lrow is a C-layout floatx4
// rescaled together with o. LDS = 43008 B -> 3 blocks/CU.
__global__ void __launch_bounds__(256, 3) flash_kernel(const __bf16* __restrict__ Qh,
                                                       const __bf16* __restrict__ Ql,
                                                       const __bf16* __restrict__ Kh,
                                                       const __bf16* __restrict__ Kl,
                                                       const __bf16* __restrict__ Vt,
                                                       __bf16* __restrict__ Mg) {
  __shared__ __align__(16) __bf16 sKh[64 * 64];
  __shared__ __align__(16) __bf16 sKl[64 * 64];
  __shared__ __align__(16) __bf16 sV[64 * 64];
  __shared__ __align__(16) __bf16 sP[4][32 * 72];

  const int tid = threadIdx.x;
  const int qt = blockIdx.x & 15;      // 16 q-tiles of 128
  const int bh = blockIdx.x >> 4;      // 64 (b,h) pairs
  const int b = bh >> 4;
  const int h = bh & 15;
  const int mq0 = b * SEQ + qt * 128;
  const int ch = h * 64;
  const int w = tid >> 6;
  const int lane = tid & 63;
  const int lm = lane & 15;
  const int q4 = lane >> 4;

  // staging geometry: two 16B chunks per thread, swizzle chunk ^ (row&7)
  const int c0 = tid, c1 = tid + 256;
  const int r0 = c0 >> 3, e0 = ((c0 & 7) ^ (r0 & 7)) << 3;
  const int r1 = c1 >> 3, e1 = ((c1 & 7) ^ (r1 & 7)) << 3;

  // prologue: stage Q (128 rows) in 2 passes of 64 through the K buffers -> regs
  bf16x8 qh[2][2], ql[2][2];  // [mi][ks]
#pragma unroll
  for (int p = 0; p < 2; ++p) {
    const size_t gq0 = (size_t)(mq0 + p * 64 + r0) * DM + ch + e0;
    const size_t gq1 = (size_t)(mq0 + p * 64 + r1) * DM + ch + e1;
    async16(Qh + gq0, &sKh[c0 * 8]);
    async16(Ql + gq0, &sKl[c0 * 8]);
    async16(Qh + gq1, &sKh[c1 * 8]);
    async16(Ql + gq1, &sKl[c1 * 8]);
    __syncthreads();
    if ((w >> 1) == p) {
#pragma unroll
      for (int mi = 0; mi < 2; ++mi) {
        const int rq = (w & 1) * 32 + mi * 16 + lm;  // row within this 64-row pass
#pragma unroll
        for (int ks = 0; ks < 2; ++ks) {
          const int oq = rq * 64 + (((ks * 4 + q4) ^ (rq & 7)) << 3);
          qh[mi][ks] = *(const bf16x8*)&sKh[oq];
          ql[mi][ks] = *(const bf16x8*)&sKl[oq];
        }
      }
    }
    __syncthreads();
  }

  // hoisted K/V fragment LDS offsets (same formula both)
  int ofr[2][4];
#pragma unroll
  for (int ks = 0; ks < 2; ++ks)
#pragma unroll
    for (int t = 0; t < 4; ++t) {
      const int rk = t * 16 + lm;
      ofr[ks][t] = rk * 64 + (((ks * 4 + q4) ^ (rk & 7)) << 3);
    }

  // ones B-fragment for the row-sum MFMA
  bf16x8 ones;
#pragma unroll
  for (int j = 0; j < 8; ++j) ones[j] = (__bf16)1.0f;

  floatx4 o[2][4], lsum[2];
  const floatx4 fz = {0.f, 0.f, 0.f, 0.f};
#pragma unroll
  for (int mi = 0; mi < 2; ++mi) {
#pragma unroll
    for (int dt = 0; dt < 4; ++dt) o[mi][dt] = fz;
    lsum[mi] = fz;
  }
  float mrow[2][4];
#pragma unroll
  for (int mi = 0; mi < 2; ++mi)
#pragma unroll
    for (int r = 0; r < 4; ++r) mrow[mi][r] = -1e30f;

  // rolling staging offsets
  size_t gk0 = (size_t)(b * SEQ + r0) * DM + ch + e0;
  size_t gk1 = (size_t)(b * SEQ + r1) * DM + ch + e1;
  size_t gv0 = (size_t)(bh * 64 + r0) * SEQ + e0;
  size_t gv1 = (size_t)(bh * 64 + r1) * SEQ + e1;

  for (int it = 0; it < 32; ++it) {
    async16(Kh + gk0, &sKh[c0 * 8]);
    async16(Kl + gk0, &sKl[c0 * 8]);
    async16(Kh + gk1, &sKh[c1 * 8]);
    async16(Kl + gk1, &sKl[c1 * 8]);
    async16(Vt + gv0, &sV[c0 * 8]);
    async16(Vt + gv1, &sV[c1 * 8]);
    gk0 += (size_t)64 * DM;
    gk1 += (size_t)64 * DM;
    gv0 += 64;
    gv1 += 64;
    __syncthreads();

    // scores: S[32 q x 64 key] per wave, 3-term, log2 domain
    floatx4 s[2][4];
#pragma unroll
    for (int mi = 0; mi < 2; ++mi)
#pragma unroll
      for (int nt = 0; nt < 4; ++nt) s[mi][nt] = fz;
#pragma unroll
    for (int ks = 0; ks < 2; ++ks) {
#pragma unroll
      for (int nt = 0; nt < 4; ++nt) {
        const bf16x8 kh = *(const bf16x8*)&sKh[ofr[ks][nt]];
        const bf16x8 kl = *(const bf16x8*)&sKl[ofr[ks][nt]];
#pragma unroll
        for (int mi = 0; mi < 2; ++mi) {
          s[mi][nt] = mfma16(qh[mi][ks], kh, s[mi][nt]);
          s[mi][nt] = mfma16(qh[mi][ks], kl, s[mi][nt]);
          s[mi][nt] = mfma16(ql[mi][ks], kh, s[mi][nt]);
        }
      }
    }

    // online softmax (base-2); rows q = mi*16 + q4*4 + r, DPP max-reduce over 16 lanes
    float mnew[2][4];
    bool upd = false;
#pragma unroll
    for (int mi = 0; mi < 2; ++mi)
#pragma unroll
      for (int r = 0; r < 4; ++r) {
        float mx = fmaxf(fmaxf(s[mi][0][r], s[mi][1][r]), fmaxf(s[mi][2][r], s[mi][3][r]));
        mx = red16_max(mx);
        mnew[mi][r] = fmaxf(mrow[mi][r], mx);
        upd = upd || (mnew[mi][r] > mrow[mi][r]);
      }
    if (__ballot(upd)) {
#pragma unroll
      for (int mi = 0; mi < 2; ++mi)
#pragma unroll
        for (int r = 0; r < 4; ++r) {
          const float a = __builtin_amdgcn_exp2f(mrow[mi][r] - mnew[mi][r]);
          mrow[mi][r] = mnew[mi][r];
          lsum[mi][r] *= a;
#pragma unroll
          for (int dt = 0; dt < 4; ++dt) o[mi][dt][r] *= a;
        }
    }
    // P = exp2(s - m) -> bf16 -> LDS (sum handled by ones-MFMA below)
#pragma unroll
    for (int mi = 0; mi < 2; ++mi)
#pragma unroll
      for (int r = 0; r < 4; ++r) {
        const int prow = mi * 16 + q4 * 4 + r;
#pragma unroll
        for (int nt = 0; nt < 4; ++nt)
          sP[w][prow * 72 + nt * 16 + lm] =
              (__bf16)__builtin_amdgcn_exp2f(s[mi][nt][r] - mrow[mi][r]);
      }

    // PV + row-sum: A = P (own wave's LDS), B = V^T tile / ones
#pragma unroll
    for (int ks = 0; ks < 2; ++ks) {
      bf16x8 a[2];
#pragma unroll
      for (int mi = 0; mi < 2; ++mi) {
        a[mi] = *(const bf16x8*)&sP[w][(mi * 16 + lm) * 72 + ks * 32 + q4 * 8];
        lsum[mi] = mfma16(a[mi], ones, lsum[mi]);
      }
#pragma unroll
      for (int dt = 0; dt < 4; ++dt) {
        const bf16x8 bv = *(const bf16x8*)&sV[ofr[ks][dt]];
#pragma unroll
        for (int mi = 0; mi < 2; ++mi)
          o[mi][dt] = mfma16(a[mi], bv, o[mi][dt]);
      }
    }
    __syncthreads();
  }

  // epilogue: normalize and store merged [B*S, D] bf16
#pragma unroll
  for (int mi = 0; mi < 2; ++mi)
#pragma unroll
    for (int r = 0; r < 4; ++r) {
      const float inv = __builtin_amdgcn_rcpf(lsum[mi][r]);
      const int gr = mq0 + w * 32 + mi * 16 + q4 * 4 + r;
#pragma unroll
      for (int dt = 0; dt < 4; ++dt)
        Mg[(size_t)gr * DM + ch + dt * 16 + lm] = (__bf16)(o[mi][dt][r] * inv);
    }
}

// ---------------- launch ----------------

extern "C" void kernel_launch(void* const* d_in, const int* in_sizes, int n_in,
                              void* d_out, int out_size, void* d_ws, size_t ws_size,
                              hipStream_t stream) {
  (void)in_sizes; (void)n_in; (void)out_size; (void)ws_size;
  const float* x  = (const float*)d_in[0];
  const float* Wq = (const float*)d_in[1];
  const float* Wk = (const float*)d_in[2];
  const float* Wv = (const float*)d_in[3];
  const float* fc = (const float*)d_in[4];
  float* out = (float*)d_out;

  char* base = (char*)d_ws;
  const size_t XB = (size_t)MROWS * DM * 2;  // 16 MiB
  const size_t WB = (size_t)DM * DM * 2;     // 2 MiB
  __bf16* xh  = (__bf16*)(base);
  __bf16* xl  = (__bf16*)(base + XB);
  __bf16* wqh = (__bf16*)(base + 2 * XB);
  __bf16* wql = (__bf16*)(base + 2 * XB + WB);
  __bf16* wkh = (__bf16*)(base + 2 * XB + 2 * WB);
  __bf16* wkl = (__bf16*)(base + 2 * XB + 3 * WB);
  __bf16* wvh = (__bf16*)(base + 2 * XB + 4 * WB);
  __bf16* fch = (__bf16*)(base + 2 * XB + 5 * WB);
  __bf16* Qh  = (__bf16*)(base + 2 * XB + 6 * WB);
  __bf16* Ql  = (__bf16*)(base + 3 * XB + 6 * WB);
  __bf16* Kh  = (__bf16*)(base + 4 * XB + 6 * WB);
  __bf16* Kl  = (__bf16*)(base + 5 * XB + 6 * WB);
  __bf16* Vt  = xl;  // xl dead after QK projection
  __bf16* Mg  = xh;  // xh dead after V projection

  split_x_kernel<<<dim3(8192), dim3(256), 0, stream>>>(x, xh, xl);
  wtrans_kernel<<<dim3(1024), dim3(256), 0, stream>>>(Wq, wqh, wql);
  wtrans_kernel<<<dim3(1024), dim3(256), 0, stream>>>(Wk, wkh, wkl);
  wtrans_kernel<<<dim3(1024), dim3(256), 0, stream>>>(Wv, wvh, (__bf16*)nullptr);
  wtrans_kernel<<<dim3(1024), dim3(256), 0, stream>>>(fc, fch, (__bf16*)nullptr);

  // fused Q+K projection (Q pre-scaled by 0.125*log2(e) for base-2 flash softmax)
  gemm_qk<<<dim3(512), dim3(256), 0, stream>>>(xh, xl, wqh, wql, wkh, wkl, Qh, Ql, Kh, Kl);
  gemm_nt<3><<<dim3(512), dim3(256), 0, stream>>>(xh, wvh, (void*)Vt);

  flash_kernel<<<dim3(1024), dim3(256), 0, stream>>>(Qh, Ql, Kh, Kl, Vt, Mg);

  gemm_nt<1><<<dim3(512), dim3(256), 0, stream>>>(Mg, fch, (void*)out);
}